// Round 4
// baseline (387.380 us; speedup 1.0000x reference)
//
#include <hip/hip_runtime.h>

#define NBINS 1001
#define HIST_BLOCK 1024
#define ELEMS_PER_BLOCK 32768   // 1024 threads x 8 float4
#define NCOPIES 64              // global-privatized histogram copies (split path)
#define COPY_STRIDE (4 * NBINS) // u64s per copy: [C][NBINS]

__device__ __forceinline__ int bin_of(float v) {
    // idx = #{ j in [0,999] : j/999 < v } = clamp(ceil(999*v), 0, 1000)
    // double keeps 999*v exact for fp32 v -> bit-exact vs reference searchsorted
    double d = ceil((double)v * 999.0);
    int k = (int)d;
    if (k < 0) k = 0;
    if (k > 1000) k = 1000;
    return k;
}

// Hybrid scatter: waves 0-2 of each 4 use LDS atomics (DS pipe), wave 3 uses
// global u64 atomics into a block-private L2-resident copy (TCC atomic pipe).
// Theory: DS unit serializes scattered atomic lanes (~1/cyc/CU); splitting the
// 16.7M lane-ops across two pipes cuts the critical path.
__global__ __launch_bounds__(HIST_BLOCK, 4) void hist_kernel(
    const float* __restrict__ x, const float* __restrict__ y,
    unsigned long long* __restrict__ ghist,
    unsigned long long* __restrict__ gcopies,
    int HW, int use_split)
{
    __shared__ unsigned int lh[NBINS];
    const int tid = threadIdx.x;
    if (tid < NBINS) lh[tid] = 0u;
    __syncthreads();

    const long long start = (long long)blockIdx.x * ELEMS_PER_BLOCK;
    const int c = (int)((start / HW) & 3);   // 32768 | HW=262144: block is class-uniform

    const float4* __restrict__ x4 = (const float4*)(x + start);
    const float4* __restrict__ y4 = (const float4*)(y + start);

    const int wave = tid >> 6;
    const bool go_global = use_split && ((wave & 3) == 3);
    unsigned long long* gcopy =
        gcopies + (size_t)(blockIdx.x & (NCOPIES - 1)) * COPY_STRIDE + (size_t)c * NBINS;

    #pragma unroll
    for (int r = 0; r < 2; ++r) {
        float4 xv[4], yv[4];
        #pragma unroll
        for (int k = 0; k < 4; ++k) {
            const int idx = (r * 4 + k) * HIST_BLOCK + tid;  // coalesced
            xv[k] = x4[idx];
            yv[k] = y4[idx];
        }
        if (go_global) {
            #pragma unroll
            for (int k = 0; k < 4; ++k) {
                atomicAdd(&gcopy[bin_of(xv[k].x)], 1ULL + ((yv[k].x > 0.5f) ? (1ULL << 32) : 0ULL));
                atomicAdd(&gcopy[bin_of(xv[k].y)], 1ULL + ((yv[k].y > 0.5f) ? (1ULL << 32) : 0ULL));
                atomicAdd(&gcopy[bin_of(xv[k].z)], 1ULL + ((yv[k].z > 0.5f) ? (1ULL << 32) : 0ULL));
                atomicAdd(&gcopy[bin_of(xv[k].w)], 1ULL + ((yv[k].w > 0.5f) ? (1ULL << 32) : 0ULL));
            }
        } else {
            #pragma unroll
            for (int k = 0; k < 4; ++k) {
                atomicAdd(&lh[bin_of(xv[k].x)], 1u + ((yv[k].x > 0.5f) ? 0x10000u : 0u));
                atomicAdd(&lh[bin_of(xv[k].y)], 1u + ((yv[k].y > 0.5f) ? 0x10000u : 0u));
                atomicAdd(&lh[bin_of(xv[k].z)], 1u + ((yv[k].z > 0.5f) ? 0x10000u : 0u));
                atomicAdd(&lh[bin_of(xv[k].w)], 1u + ((yv[k].w > 0.5f) ? 0x10000u : 0u));
            }
        }
    }
    __syncthreads();

    // Flush LDS histogram: unpack u32 -> u64 (low32 = count, high32 = pos count)
    if (tid < NBINS) {
        unsigned int v = lh[tid];
        if (v) {
            unsigned long long add = (unsigned long long)(v & 0xffffu)
                                   | ((unsigned long long)(v >> 16) << 32);
            atomicAdd(&ghist[(size_t)c * NBINS + tid], add);
        }
    }
}

// One block, 1024 threads; thread t owns bin t for all 4 classes.
__global__ __launch_bounds__(1024) void f1_kernel(
    const unsigned long long* __restrict__ ghist,
    const unsigned long long* __restrict__ gcopies,
    float* __restrict__ out, int use_split)
{
    __shared__ unsigned long long wtot[4][16];
    __shared__ float wmax[4][16];
    const int tid  = threadIdx.x;
    const int lane = tid & 63;
    const int wave = tid >> 6;

    unsigned long long v[4];
    #pragma unroll
    for (int c = 0; c < 4; ++c)
        v[c] = (tid < NBINS) ? ghist[(size_t)c * NBINS + tid] : 0ULL;

    if (use_split && tid < NBINS) {
        // fold in the 64 global-privatized copies (coalesced across lanes per j)
        for (int j = 0; j < NCOPIES; ++j) {
            const unsigned long long* cp = gcopies + (size_t)j * COPY_STRIDE + tid;
            #pragma unroll
            for (int c = 0; c < 4; ++c) v[c] += cp[(size_t)c * NBINS];
        }
    }

    // intra-wave inclusive scan (u64, packed cnt | ycnt<<32 - fields can't interact)
    #pragma unroll
    for (int off = 1; off < 64; off <<= 1) {
        #pragma unroll
        for (int c = 0; c < 4; ++c) {
            unsigned long long t = __shfl_up(v[c], off, 64);
            if (lane >= off) v[c] += t;
        }
    }
    if (lane == 63) {
        #pragma unroll
        for (int c = 0; c < 4; ++c) wtot[c][wave] = v[c];
    }
    __syncthreads();

    // wave 0: inclusive scan of the 16 wave totals per class (lane = c*16 + w)
    if (wave == 0) {
        const int c = lane >> 4, w = lane & 15;
        unsigned long long t = wtot[c][w];
        #pragma unroll
        for (int off = 1; off < 16; off <<= 1) {
            unsigned long long s = __shfl_up(t, off, 16);
            if (w >= off) t += s;
        }
        wtot[c][w] = t;
    }
    __syncthreads();

    float m[4];
    #pragma unroll
    for (int c = 0; c < 4; ++c) {
        unsigned long long cum = v[c];
        if (wave > 0) cum += wtot[c][wave - 1];
        unsigned long long tot = wtot[c][15];
        unsigned int total_cnt = (unsigned int)(tot & 0xffffffffULL);  // N per class
        unsigned int total_y   = (unsigned int)(tot >> 32);
        float f1 = 0.0f;
        if (tid < NBINS - 1) {  // thresholds k = 0..999
            unsigned int cnt_cum = (unsigned int)(cum & 0xffffffffULL);
            unsigned int y_cum   = (unsigned int)(cum >> 32);
            unsigned int TP = total_y - y_cum;
            unsigned int PP = total_cnt - cnt_cum;
            unsigned int denom = total_y + PP;  // = 2*(TP + 0.5*(FN+FP))
            f1 = (denom == 0u) ? 0.0f : (2.0f * (float)TP) / (float)denom;
        }
        m[c] = f1;
    }

    // wave max-reduce per class
    #pragma unroll
    for (int off = 32; off > 0; off >>= 1) {
        #pragma unroll
        for (int c = 0; c < 4; ++c)
            m[c] = fmaxf(m[c], __shfl_down(m[c], off, 64));
    }
    if (lane == 0) {
        #pragma unroll
        for (int c = 0; c < 4; ++c) wmax[c][wave] = m[c];
    }
    __syncthreads();

    if (tid == 0) {
        float loss = 0.0f;
        #pragma unroll
        for (int c = 0; c < 4; ++c) {
            float mm = wmax[c][0];
            #pragma unroll
            for (int w = 1; w < 16; ++w) mm = fmaxf(mm, wmax[c][w]);
            loss += 1.0f - mm;
        }
        out[0] = loss * 0.25f;
    }
}

extern "C" void kernel_launch(void* const* d_in, const int* in_sizes, int n_in,
                              void* d_out, int out_size, void* d_ws, size_t ws_size,
                              hipStream_t stream) {
    const float* x = (const float*)d_in[0];
    const float* y = (const float*)d_in[1];
    float* out = (float*)d_out;

    const int H = 512, W = 512;
    const int HW = H * W;
    const long long total = (long long)in_sizes[0];   // 16777216

    // d_ws layout: [ghist: 4*1001 u64][gcopies: 64 * 4*1001 u64]
    unsigned long long* ghist   = (unsigned long long*)d_ws;
    unsigned long long* gcopies = ghist + COPY_STRIDE;
    const size_t need = (size_t)(1 + NCOPIES) * COPY_STRIDE * sizeof(unsigned long long);
    const int use_split = (ws_size >= need) ? 1 : 0;
    const size_t zbytes = use_split ? need : (size_t)COPY_STRIDE * sizeof(unsigned long long);

    hipMemsetAsync(d_ws, 0, zbytes, stream);

    const int nblocks = (int)(total / ELEMS_PER_BLOCK);  // 512
    hist_kernel<<<nblocks, HIST_BLOCK, 0, stream>>>(x, y, ghist, gcopies, HW, use_split);
    f1_kernel<<<1, 1024, 0, stream>>>(ghist, gcopies, out, use_split);
    (void)n_in; (void)out_size;
}

// Round 5
// 152.491 us; speedup vs baseline: 2.5404x; 2.5404x over previous
//
#include <hip/hip_runtime.h>

#define NBINS 1001
#define HIST_BLOCK 1024
#define ELEMS_PER_BLOCK 32768   // 1024 threads x 8 float4

__device__ __forceinline__ int bin_of(float v) {
    // idx = #{ j in [0,999] : fp32(j/999) < v } ~= clamp(ceil(999*v), 0, 1000)
    // fp32 rounding can flip a bin only when 999*v is within ~6e-5 of an integer
    // (~1e3 of 16.7M elems); each flip moves F1 by ~1e-6 << 1.08e-2 tolerance.
    int k = (int)ceilf(v * 999.0f);
    k = (k < 0) ? 0 : k;
    k = (k > 1000) ? 1000 : k;
    return k;
}

// Pure-LDS histogram (global-atomic leg reverted: R4 showed device-scope
// atomics run at ~17 G/s and thrash HBM writes). Two sub-histograms (even/odd
// waves) halve same-address atomic collisions and RMW bank re-hits.
// Packed u32 bins: low16 = count, high16 = positive count; each sub-hist sees
// <= 16384 elements so fields can't overflow.
__global__ __launch_bounds__(HIST_BLOCK, 4) void hist_kernel(
    const float* __restrict__ x, const float* __restrict__ y,
    unsigned long long* __restrict__ ghist, int HW)
{
    __shared__ unsigned int lh[2][NBINS];
    const int tid = threadIdx.x;
    if (tid < NBINS) { lh[0][tid] = 0u; lh[1][tid] = 0u; }
    __syncthreads();

    const long long start = (long long)blockIdx.x * ELEMS_PER_BLOCK;
    const int c = (int)((start / HW) & 3);   // 32768 | HW=262144: block is class-uniform

    const float4* __restrict__ x4 = (const float4*)(x + start);
    const float4* __restrict__ y4 = (const float4*)(y + start);

    unsigned int* __restrict__ h = lh[(tid >> 6) & 1];   // even/odd wave split

    #pragma unroll
    for (int r = 0; r < 2; ++r) {
        float4 xv[4], yv[4];
        #pragma unroll
        for (int k = 0; k < 4; ++k) {
            const int idx = (r * 4 + k) * HIST_BLOCK + tid;  // coalesced
            xv[k] = x4[idx];
            yv[k] = y4[idx];
        }
        #pragma unroll
        for (int k = 0; k < 4; ++k) {
            // y is exactly 0.0f or 1.0f: bits(1.0f)=0x3f800000 -> (>>8)&0x10000
            atomicAdd(&h[bin_of(xv[k].x)], 1u + ((__float_as_uint(yv[k].x) >> 8) & 0x10000u));
            atomicAdd(&h[bin_of(xv[k].y)], 1u + ((__float_as_uint(yv[k].y) >> 8) & 0x10000u));
            atomicAdd(&h[bin_of(xv[k].z)], 1u + ((__float_as_uint(yv[k].z) >> 8) & 0x10000u));
            atomicAdd(&h[bin_of(xv[k].w)], 1u + ((__float_as_uint(yv[k].w) >> 8) & 0x10000u));
        }
    }
    __syncthreads();

    // Flush: merge sub-histograms, unpack u32 -> u64 (low32=cnt, high32=pos)
    if (tid < NBINS) {
        unsigned int v = lh[0][tid] + lh[1][tid];
        if (v) {
            unsigned long long add = (unsigned long long)(v & 0xffffu)
                                   | ((unsigned long long)(v >> 16) << 32);
            atomicAdd(&ghist[(size_t)c * NBINS + tid], add);
        }
    }
}

// One block, 1024 threads; thread t owns bin t for all 4 classes.
__global__ __launch_bounds__(1024) void f1_kernel(
    const unsigned long long* __restrict__ ghist, float* __restrict__ out)
{
    __shared__ unsigned long long wtot[4][16];
    __shared__ float wmax[4][16];
    const int tid  = threadIdx.x;
    const int lane = tid & 63;
    const int wave = tid >> 6;

    unsigned long long v[4];
    #pragma unroll
    for (int c = 0; c < 4; ++c)
        v[c] = (tid < NBINS) ? ghist[(size_t)c * NBINS + tid] : 0ULL;

    // intra-wave inclusive scan (u64, packed cnt | ycnt<<32 - fields can't interact)
    #pragma unroll
    for (int off = 1; off < 64; off <<= 1) {
        #pragma unroll
        for (int c = 0; c < 4; ++c) {
            unsigned long long t = __shfl_up(v[c], off, 64);
            if (lane >= off) v[c] += t;
        }
    }
    if (lane == 63) {
        #pragma unroll
        for (int c = 0; c < 4; ++c) wtot[c][wave] = v[c];
    }
    __syncthreads();

    // wave 0: inclusive scan of the 16 wave totals per class (lane = c*16 + w)
    if (wave == 0) {
        const int c = lane >> 4, w = lane & 15;
        unsigned long long t = wtot[c][w];
        #pragma unroll
        for (int off = 1; off < 16; off <<= 1) {
            unsigned long long s = __shfl_up(t, off, 16);
            if (w >= off) t += s;
        }
        wtot[c][w] = t;
    }
    __syncthreads();

    float m[4];
    #pragma unroll
    for (int c = 0; c < 4; ++c) {
        unsigned long long cum = v[c];
        if (wave > 0) cum += wtot[c][wave - 1];
        unsigned long long tot = wtot[c][15];
        unsigned int total_cnt = (unsigned int)(tot & 0xffffffffULL);  // N per class
        unsigned int total_y   = (unsigned int)(tot >> 32);
        float f1 = 0.0f;
        if (tid < NBINS - 1) {  // thresholds k = 0..999
            unsigned int cnt_cum = (unsigned int)(cum & 0xffffffffULL);
            unsigned int y_cum   = (unsigned int)(cum >> 32);
            unsigned int TP = total_y - y_cum;
            unsigned int PP = total_cnt - cnt_cum;
            unsigned int denom = total_y + PP;  // = 2*(TP + 0.5*(FN+FP))
            f1 = (denom == 0u) ? 0.0f : (2.0f * (float)TP) / (float)denom;
        }
        m[c] = f1;
    }

    // wave max-reduce per class
    #pragma unroll
    for (int off = 32; off > 0; off >>= 1) {
        #pragma unroll
        for (int c = 0; c < 4; ++c)
            m[c] = fmaxf(m[c], __shfl_down(m[c], off, 64));
    }
    if (lane == 0) {
        #pragma unroll
        for (int c = 0; c < 4; ++c) wmax[c][wave] = m[c];
    }
    __syncthreads();

    if (tid == 0) {
        float loss = 0.0f;
        #pragma unroll
        for (int c = 0; c < 4; ++c) {
            float mm = wmax[c][0];
            #pragma unroll
            for (int w = 1; w < 16; ++w) mm = fmaxf(mm, wmax[c][w]);
            loss += 1.0f - mm;
        }
        out[0] = loss * 0.25f;
    }
}

extern "C" void kernel_launch(void* const* d_in, const int* in_sizes, int n_in,
                              void* d_out, int out_size, void* d_ws, size_t ws_size,
                              hipStream_t stream) {
    const float* x = (const float*)d_in[0];
    const float* y = (const float*)d_in[1];
    float* out = (float*)d_out;

    const int H = 512, W = 512;
    const int HW = H * W;
    const long long total = (long long)in_sizes[0];   // 16777216

    unsigned long long* ghist = (unsigned long long*)d_ws;

    hipMemsetAsync(d_ws, 0, (size_t)4 * NBINS * sizeof(unsigned long long), stream);

    const int nblocks = (int)(total / ELEMS_PER_BLOCK);  // 512
    hist_kernel<<<nblocks, HIST_BLOCK, 0, stream>>>(x, y, ghist, HW);
    f1_kernel<<<1, 1024, 0, stream>>>(ghist, out);
    (void)n_in; (void)out_size; (void)ws_size;
}

// Round 7
// 147.201 us; speedup vs baseline: 2.6316x; 1.0359x over previous
//
#include <hip/hip_runtime.h>

#define NBINS 1001
#define HIST_BLOCK 256
#define VPT 8                                     // float4s of x (and of y) per thread
#define ELEMS_PER_BLOCK (HIST_BLOCK * VPT * 4)    // 8192 -> 2048 blocks

typedef float fvec4 __attribute__((ext_vector_type(4)));   // clang vector: ok for nontemporal builtins

__device__ __forceinline__ int bin_of(float v) {
    // idx = #{ j in [0,999] : fp32(j/999) < v } ~= clamp(ceil(999*v), 0, 1000)
    // fp32 rounding flips a bin only when 999*v is within ~6e-5 of an integer
    // (~1e3 of 16.7M elems); each flip moves F1 by ~1e-6 << 1.08e-2 tolerance.
    int k = (int)ceilf(v * 999.0f);
    k = (k < 0) ? 0 : k;
    k = (k > 1000) ? 1000 : k;
    return k;
}

// Phase-overlap experiment: ALL 16 nontemporal loads issued before the LDS
// init barrier (16 KB outstanding per wave through the barrier), then the
// atomic phase runs while other waves' loads are still in flight.
// Packed u32 bins: low16 = count, high16 = positive count (block sees 8192
// elems -> no overflow). One LDS atomic per element is the scatter minimum.
__global__ __launch_bounds__(HIST_BLOCK) void hist_kernel(
    const float* __restrict__ x, const float* __restrict__ y,
    unsigned long long* __restrict__ ghist, int HW)
{
    __shared__ unsigned int lh[NBINS];
    const int tid = threadIdx.x;

    const long long start = (long long)blockIdx.x * ELEMS_PER_BLOCK;
    const int c = (int)((start / HW) & 3);   // 8192 | HW=262144: block is class-uniform

    const fvec4* __restrict__ x4 = (const fvec4*)(x + start);
    const fvec4* __restrict__ y4 = (const fvec4*)(y + start);

    // Issue the whole memory phase first (single-use data -> nontemporal).
    fvec4 xv[VPT], yv[VPT];
    #pragma unroll
    for (int k = 0; k < VPT; ++k) {
        const int idx = k * HIST_BLOCK + tid;    // lanes contiguous: coalesced
        xv[k] = __builtin_nontemporal_load(&x4[idx]);
        yv[k] = __builtin_nontemporal_load(&y4[idx]);
    }

    // LDS init + barrier overlap the in-flight loads.
    for (int i = tid; i < NBINS; i += HIST_BLOCK) lh[i] = 0u;
    __syncthreads();

    #pragma unroll
    for (int k = 0; k < VPT; ++k) {
        // y is exactly 0.0f or 1.0f: bits(1.0f)=0x3f800000 -> (>>8)&0x10000
        atomicAdd(&lh[bin_of(xv[k].x)], 1u + ((__float_as_uint(yv[k].x) >> 8) & 0x10000u));
        atomicAdd(&lh[bin_of(xv[k].y)], 1u + ((__float_as_uint(yv[k].y) >> 8) & 0x10000u));
        atomicAdd(&lh[bin_of(xv[k].z)], 1u + ((__float_as_uint(yv[k].z) >> 8) & 0x10000u));
        atomicAdd(&lh[bin_of(xv[k].w)], 1u + ((__float_as_uint(yv[k].w) >> 8) & 0x10000u));
    }
    __syncthreads();

    // Flush: unpack u32 -> u64 (low32 = count, high32 = positive count)
    for (int i = tid; i < NBINS; i += HIST_BLOCK) {
        unsigned int v = lh[i];
        if (v) {
            unsigned long long add = (unsigned long long)(v & 0xffffu)
                                   | ((unsigned long long)(v >> 16) << 32);
            atomicAdd(&ghist[(size_t)c * NBINS + i], add);
        }
    }
}

// One block, 1024 threads; thread t owns bin t for all 4 classes.
__global__ __launch_bounds__(1024) void f1_kernel(
    const unsigned long long* __restrict__ ghist, float* __restrict__ out)
{
    __shared__ unsigned long long wtot[4][16];
    __shared__ float wmax[4][16];
    const int tid  = threadIdx.x;
    const int lane = tid & 63;
    const int wave = tid >> 6;

    unsigned long long v[4];
    #pragma unroll
    for (int c = 0; c < 4; ++c)
        v[c] = (tid < NBINS) ? ghist[(size_t)c * NBINS + tid] : 0ULL;

    // intra-wave inclusive scan (u64, packed cnt | ycnt<<32 - fields can't interact)
    #pragma unroll
    for (int off = 1; off < 64; off <<= 1) {
        #pragma unroll
        for (int c = 0; c < 4; ++c) {
            unsigned long long t = __shfl_up(v[c], off, 64);
            if (lane >= off) v[c] += t;
        }
    }
    if (lane == 63) {
        #pragma unroll
        for (int c = 0; c < 4; ++c) wtot[c][wave] = v[c];
    }
    __syncthreads();

    // wave 0: inclusive scan of the 16 wave totals per class (lane = c*16 + w)
    if (wave == 0) {
        const int c = lane >> 4, w = lane & 15;
        unsigned long long t = wtot[c][w];
        #pragma unroll
        for (int off = 1; off < 16; off <<= 1) {
            unsigned long long s = __shfl_up(t, off, 16);
            if (w >= off) t += s;
        }
        wtot[c][w] = t;
    }
    __syncthreads();

    float m[4];
    #pragma unroll
    for (int c = 0; c < 4; ++c) {
        unsigned long long cum = v[c];
        if (wave > 0) cum += wtot[c][wave - 1];
        unsigned long long tot = wtot[c][15];
        unsigned int total_cnt = (unsigned int)(tot & 0xffffffffULL);  // N per class
        unsigned int total_y   = (unsigned int)(tot >> 32);
        float f1 = 0.0f;
        if (tid < NBINS - 1) {  // thresholds k = 0..999
            unsigned int cnt_cum = (unsigned int)(cum & 0xffffffffULL);
            unsigned int y_cum   = (unsigned int)(cum >> 32);
            unsigned int TP = total_y - y_cum;
            unsigned int PP = total_cnt - cnt_cum;
            unsigned int denom = total_y + PP;  // = 2*(TP + 0.5*(FN+FP))
            f1 = (denom == 0u) ? 0.0f : (2.0f * (float)TP) / (float)denom;
        }
        m[c] = f1;
    }

    // wave max-reduce per class
    #pragma unroll
    for (int off = 32; off > 0; off >>= 1) {
        #pragma unroll
        for (int c = 0; c < 4; ++c)
            m[c] = fmaxf(m[c], __shfl_down(m[c], off, 64));
    }
    if (lane == 0) {
        #pragma unroll
        for (int c = 0; c < 4; ++c) wmax[c][wave] = m[c];
    }
    __syncthreads();

    if (tid == 0) {
        float loss = 0.0f;
        #pragma unroll
        for (int c = 0; c < 4; ++c) {
            float mm = wmax[c][0];
            #pragma unroll
            for (int w = 1; w < 16; ++w) mm = fmaxf(mm, wmax[c][w]);
            loss += 1.0f - mm;
        }
        out[0] = loss * 0.25f;
    }
}

extern "C" void kernel_launch(void* const* d_in, const int* in_sizes, int n_in,
                              void* d_out, int out_size, void* d_ws, size_t ws_size,
                              hipStream_t stream) {
    const float* x = (const float*)d_in[0];
    const float* y = (const float*)d_in[1];
    float* out = (float*)d_out;

    const int H = 512, W = 512;
    const int HW = H * W;
    const long long total = (long long)in_sizes[0];   // 16777216

    unsigned long long* ghist = (unsigned long long*)d_ws;

    (void)hipMemsetAsync(d_ws, 0, (size_t)4 * NBINS * sizeof(unsigned long long), stream);

    const int nblocks = (int)(total / ELEMS_PER_BLOCK);  // 2048
    hist_kernel<<<nblocks, HIST_BLOCK, 0, stream>>>(x, y, ghist, HW);
    f1_kernel<<<1, 1024, 0, stream>>>(ghist, out);
    (void)n_in; (void)out_size; (void)ws_size;
}